// Round 6
// baseline (416.629 us; speedup 1.0000x reference)
//
#include <hip/hip_runtime.h>
#include <math.h>

// Problem constants: B=64/side (128 concat), d=256, C=128, S=1024, TEMP=0.1, COEFF=0.5
#define TEMP_INV 10.0f

typedef unsigned long long u64;
typedef __attribute__((ext_vector_type(8))) __bf16 bf16x8;
typedef __attribute__((ext_vector_type(4))) float f32x4;

// Monotone u32 key: fkey(a) > fkey(b) iff a > b (floats, no NaN).
__device__ inline unsigned fkey(float v) {
  unsigned u = __float_as_uint(v);
  return (u & 0x80000000u) ? ~u : (u | 0x80000000u);
}

// async global->LDS, 16B per lane (wave-uniform base + lane*16 ordering).
__device__ __forceinline__ void async_copy16(const void* gp, void* lp) {
  __builtin_amdgcn_global_load_lds(
      (__attribute__((address_space(1))) void*)(unsigned long long)gp,
      (__attribute__((address_space(3))) void*)(unsigned long long)lp,
      16, 0, 0);
}

// ---------- merged prologue: kcvt [0,4096) + kprep [4096,4672) + kglobal [4672,4736) ----------
// All three are mutually independent; merging overlaps their tails and saves
// two dispatch gaps. Per-block code identical to the previous split kernels.
__global__ __launch_bounds__(256) void kpre(
    const float* __restrict__ ofq, const float* __restrict__ ofk,
    __bf16* __restrict__ ofT, float* __restrict__ of_invn,
    const float* __restrict__ xq, const float* __restrict__ xk,
    float* __restrict__ x_invn,
    const float* __restrict__ adq, const float* __restrict__ adk,
    float* __restrict__ adt,
    const float* __restrict__ agq, const float* __restrict__ agk,
    float* __restrict__ gsum) {
  unsigned bx = blockIdx.x;
  int t = threadIdx.x;
  if (bx < 4096) {
    // ---- kcvt: fused transpose + bf16 convert + norms ----
    int s0 = (bx & 31) * 32, b = bx >> 5;
    const float* src = (b < 64) ? (ofq + (size_t)b * 262144) : (ofk + (size_t)(b - 64) * 262144);
    __shared__ __bf16 T[32][36];
    __shared__ float R[8][32];
    int dd = t >> 5, ss = t & 31;
    int wr = t >> 3, wd = t & 7;
    float ssq = 0.f;
    __bf16* out = ofT + (size_t)b * 262144 + (size_t)s0 * 256;
    for (int d0 = 0; d0 < 256; d0 += 32) {
      float v[4];
#pragma unroll
      for (int it = 0; it < 4; ++it) {
        int d = d0 + dd + 8 * it;
        v[it] = src[(size_t)d * 1024 + s0 + ss];
        ssq += v[it] * v[it];
      }
      __syncthreads();
#pragma unroll
      for (int it = 0; it < 4; ++it) T[ss][dd + 8 * it] = (__bf16)v[it];
      __syncthreads();
      *(uint2*)(out + (size_t)wr * 256 + d0 + wd * 4) = *(const uint2*)(&T[wr][wd * 4]);
    }
    R[dd][ss] = ssq;
    __syncthreads();
    if (t < 32) {
      float a = 0.f;
#pragma unroll
      for (int r = 0; r < 8; ++r) a += R[r][t];
      of_invn[b * 1024 + s0 + t] = 1.0f / fmaxf(sqrtf(a), 1e-12f);
    }
  } else if (bx < 4672) {
    // ---- kprep: x-norms + ad transpose ----
    unsigned px = bx - 4096;
    if (px < 512) {
      int idx = px * 256 + t;  // 0..131071
      int b = idx >> 10, s = idx & 1023;
      const float* src = (b < 64) ? (xq + (size_t)b * 131072) : (xk + (size_t)(b - 64) * 131072);
      float acc = 0.f;
#pragma unroll 8
      for (int c = 0; c < 128; ++c) { float v = src[c * 1024 + s]; acc += v * v; }
      x_invn[idx] = 1.0f / fmaxf(sqrtf(acc), 1e-12f);
    } else {
      int i = (px - 512) * 256 + t;  // 0..16383
      int dir = i >> 13, r = i & 8191;
      int j = r >> 7, c = r & 127;
      const float* ad = dir == 0 ? adk : adq;
      adt[dir * 8192 + c * 64 + j] = ad[j * 128 + c];
    }
  } else {
    // ---- kglobal: 2 rows i per block (t<128 -> i0, t>=128 -> i0+1) ----
    __shared__ float logits[2][128];
    __shared__ float rinv[128];
    int ii = t >> 7, j = t & 127;
    int i = (int)(bx - 4672) * 2 + ii;
    const float* rowi = (i < 64) ? (agq + i * 128) : (agk + (i - 64) * 128);
    const float* rowj = (j < 64) ? (agq + j * 128) : (agk + (j - 64) * 128);
    float dot = 0.f, nj = 0.f;
#pragma unroll 8
    for (int c = 0; c < 128; ++c) { float a = rowi[c], bb = rowj[c]; dot += a * bb; nj += bb * bb; }
    if (ii == 0) rinv[j] = 1.0f / fmaxf(sqrtf(nj), 1e-12f);
    __syncthreads();
    logits[ii][j] = dot * rinv[i] * rinv[j] * TEMP_INV;
    __syncthreads();
    if (j == 0) {
      int pos = (i + 64) & 127;
      float m = -INFINITY;
      for (int tt = 0; tt < 128; ++tt) if (tt != i) m = fmaxf(m, logits[ii][tt]);
      float e = 0.f;
      for (int tt = 0; tt < 128; ++tt) if (tt != i) e += __expf(logits[ii][tt] - m);
      atomicAdd(gsum, m + __logf(e) - logits[ii][pos]);
    }
  }
}

// ---------- MFMA sim GEMM + dual argmax (R5 best: 92 us, FETCH 33 MB) ----------
// 256x256 tile, 8 waves (2M x 4N), BK=64, double-buffered, G4 XOR-swizzled LDS,
// b<->XCD affinity swizzle (b-slice L2-resident on one XCD).
__global__ __launch_bounds__(512, 2) void ksim(
    const __bf16* __restrict__ ofT, const float* __restrict__ of_invn,
    u64* __restrict__ best_row, u64* __restrict__ best_col) {
  // hardware linear block id -> (xcd, slot); b % 8 == xcd; 1024 = 8 XCD x 128
  unsigned h = blockIdx.x + (blockIdx.y << 2) + (blockIdx.z << 4);
  int xcd = h & 7;
  unsigned slot = h >> 3;               // 0..127 within XCD
  int b = xcd + 8 * (int)(slot >> 4);   // 16 tiles per b
  int tile = slot & 15;
  int s0 = (tile & 3) * 256, t0 = (tile >> 2) * 256;

  const __bf16* Ag = ofT + (size_t)b * 262144;        // q rows [1024][256]
  const __bf16* Bg = ofT + (size_t)(b + 64) * 262144; // k rows
  __shared__ __bf16 As[2][16384];  // 64 KiB
  __shared__ __bf16 Bs[2][16384];  // 64 KiB  (total 128 KiB)

  int t = threadIdx.x;
  int lane = t & 63, w = t >> 6;
  int lc = lane & 15, q = lane >> 4;
  int wm = w >> 2, wn = w & 3;  // 2 x 4 wave grid; wave owns 128(M) x 64(N)

  f32x4 acc[8][4];
#pragma unroll
  for (int i = 0; i < 8; ++i)
#pragma unroll
    for (int j = 0; j < 4; ++j) acc[i][j] = (f32x4)(0.f);

  // fragment LDS offsets (bf16 units), kk=0; kk=1 reads offset ^ 32
  int aoff[8], boff[4];
#pragma unroll
  for (int i = 0; i < 8; ++i) {
    int mr = wm * 128 + i * 16 + lc;
    aoff[i] = mr * 64 + ((q ^ (mr & 7)) << 3);
  }
#pragma unroll
  for (int j = 0; j < 4; ++j) {
    int nc = wn * 64 + j * 16 + lc;
    boff[j] = nc * 64 + ((q ^ (nc & 7)) << 3);
  }

  // staging: thread t, chunk c: row m = c*64 + (t>>3), phys slot g = t&7,
  // logical group lg = g ^ (m&7) = g ^ ((t>>3)&7)  (c*64 is 0 mod 8)
  int ms = t >> 3, gphys = t & 7;
  int lg = gphys ^ (ms & 7);
  size_t aSrc = (size_t)(s0 + ms) * 256 + lg * 8;
  size_t bSrc = (size_t)(t0 + ms) * 256 + lg * 8;

  auto STAGE = [&](int bufn, int k0) {
    char* aL = (char*)&As[bufn][0] + t * 16;
    char* bL = (char*)&Bs[bufn][0] + t * 16;
#pragma unroll
    for (int c = 0; c < 4; ++c) {
      async_copy16(Ag + aSrc + (size_t)c * 16384 + k0, aL + c * 8192);
      async_copy16(Bg + bSrc + (size_t)c * 16384 + k0, bL + c * 8192);
    }
  };

  // prologue: stage k0=0 into buf 0
  STAGE(0, 0);
  __syncthreads();

  for (int it = 0; it < 4; ++it) {
    int buf = it & 1;
    if (it < 3) STAGE(buf ^ 1, (it + 1) * 64);
#pragma unroll
    for (int kk = 0; kk < 2; ++kk) {
      int kx = kk << 5;  // ^32 toggles phys k-group bit 2
      bf16x8 af[8], bfr[4];
#pragma unroll
      for (int i = 0; i < 8; ++i) af[i] = *(const bf16x8*)(&As[buf][0] + (aoff[i] ^ kx));
#pragma unroll
      for (int j = 0; j < 4; ++j) bfr[j] = *(const bf16x8*)(&Bs[buf][0] + (boff[j] ^ kx));
      __builtin_amdgcn_s_setprio(1);
#pragma unroll
      for (int i = 0; i < 8; ++i)
#pragma unroll
        for (int j = 0; j < 4; ++j)
          acc[i][j] = __builtin_amdgcn_mfma_f32_16x16x32_bf16(af[i], bfr[j], acc[i][j], 0, 0, 0);
      __builtin_amdgcn_s_setprio(0);
    }
    __syncthreads();  // readers done with buf + drains prefetch vmcnt
  }

  // ---- epilogue (f32 domain). C/D layout: col=lane&15, row=(lane>>4)*4+reg ----
  float sk[4];
#pragma unroll
  for (int j = 0; j < 4; ++j) sk[j] = of_invn[65536 + b * 1024 + t0 + wn * 64 + j * 16 + lc];
  float sq[32];
#pragma unroll
  for (int i = 0; i < 8; ++i)
#pragma unroll
    for (int e = 0; e < 4; ++e)
      sq[i * 4 + e] = of_invn[b * 1024 + s0 + wm * 128 + i * 16 + q * 4 + e];

  u64* browb = best_row + (size_t)b * 1024 + s0;
  u64* bcolb = best_col + (size_t)b * 1024 + t0;

  // row direction: argmax over t for fixed s (scale by sik only; siq>0 dropped)
#pragma unroll
  for (int i = 0; i < 8; ++i) {
#pragma unroll
    for (int e = 0; e < 4; ++e) {
      float v[4];
#pragma unroll
      for (int j = 0; j < 4; ++j) v[j] = acc[i][j][e] * sk[j];
      float vb = fmaxf(fmaxf(v[0], v[1]), fmaxf(v[2], v[3]));
#pragma unroll
      for (int mask = 1; mask <= 8; mask <<= 1) vb = fmaxf(vb, __shfl_xor(vb, mask));
      unsigned ib = 0xFFFFFFFFu;
#pragma unroll
      for (int j = 0; j < 4; ++j) {
        unsigned cand = (v[j] == vb) ? (unsigned)(t0 + wn * 64 + j * 16 + lc) : 0xFFFFFFFFu;
        ib = min(ib, cand);
      }
#pragma unroll
      for (int mask = 1; mask <= 8; mask <<= 1) ib = min(ib, __shfl_xor(ib, mask));
      if (lc == 0)
        atomicMax(browb + wm * 128 + i * 16 + q * 4 + e,
                  ((u64)fkey(vb) << 32) | (u64)(0xFFFFFFFFu - ib));
    }
  }

  // col direction: argmax over s for fixed t (scale by siq only)
#pragma unroll
  for (int j = 0; j < 4; ++j) {
    float cb = -INFINITY;
#pragma unroll
    for (int i = 0; i < 8; ++i)
#pragma unroll
      for (int e = 0; e < 4; ++e) cb = fmaxf(cb, acc[i][j][e] * sq[i * 4 + e]);
    cb = fmaxf(cb, __shfl_xor(cb, 16));
    cb = fmaxf(cb, __shfl_xor(cb, 32));
    unsigned ib = 0xFFFFFFFFu;
#pragma unroll
    for (int i = 0; i < 8; ++i)
#pragma unroll
      for (int e = 0; e < 4; ++e) {
        float m2 = acc[i][j][e] * sq[i * 4 + e];  // bitwise-identical recompute
        unsigned cand = (m2 == cb) ? (unsigned)(s0 + wm * 128 + i * 16 + q * 4 + e) : 0xFFFFFFFFu;
        ib = min(ib, cand);
      }
    ib = min(ib, __shfl_xor(ib, 16));
    ib = min(ib, __shfl_xor(ib, 32));
    if (lane < 16)
      atomicMax(bcolb + wn * 64 + j * 16 + lane,
                ((u64)fkey(cb) << 32) | (u64)(0xFFFFFFFFu - ib));
  }
}

// ---------- pos logits ----------
// R6: s-dimension split across 2 blocks (grid 64x2x2, 512 thr) -> 256 blocks
// = full GPU (was 128 blocks on 256 CUs). Per-s math order unchanged.
__global__ __launch_bounds__(512) void kpos(
    const float* __restrict__ xq, const float* __restrict__ xk,
    const float* __restrict__ x_invn,
    const u64* __restrict__ best_row, const u64* __restrict__ best_col,
    float* __restrict__ posl) {
  int b = blockIdx.x, dir = blockIdx.y, half = blockIdx.z;
  const float* xsrc = dir == 0 ? xq : xk;
  const float* xdst = dir == 0 ? xk : xq;
  const float* inv_src = x_invn + (dir ? 65536 : 0);
  const float* inv_dst = x_invn + (dir ? 0 : 65536);
  const u64* best = dir == 0 ? best_row : best_col;

  __shared__ float xrow[8][1024];  // 32KB
  __shared__ float sdinv[1024];    // 4KB
  int t = threadIdx.x;             // 0..511
  int s = half * 512 + t;
  sdinv[t] = inv_dst[b * 1024 + t];
  sdinv[t + 512] = inv_dst[b * 1024 + t + 512];
  u64 p = best[(size_t)b * 1024 + s];
  int sidx = (int)(0xFFFFFFFFu - (unsigned)(p & 0xFFFFFFFFull));
  const float* xsb = xsrc + (size_t)b * 131072;
  const float* xdb = xdst + (size_t)b * 131072;
  float acc = 0.f;
  for (int c0 = 0; c0 < 128; c0 += 8) {
    __syncthreads();
#pragma unroll
    for (int qq = 0; qq < 4; ++qq)
      ((float4*)xrow)[t + 512 * qq] = ((const float4*)(xdb + (size_t)c0 * 1024))[t + 512 * qq];
    __syncthreads();
#pragma unroll
    for (int cc = 0; cc < 8; ++cc)
      acc += xsb[(size_t)(c0 + cc) * 1024 + s] * xrow[cc][sidx];
  }
  posl[dir * 65536 + b * 1024 + s] = acc * inv_src[b * 1024 + s] * sdinv[sidx] * TEMP_INV;
}

// ---------- neg GEMM + fused logsumexp ----------
// R6: no LDS staging — A read as float4 direct from global (broadcast across
// tx lanes), B from L1-resident adt. Bit-exact vs staged version: same
// per-element x*sinv multiply, same kk-ascending FMA order, same B bytes.
// LDS -> 64 B => 8 blocks/CU, 32 waves/CU (whole kneg resident in one round).
__global__ __launch_bounds__(256) void kneg(
    const float* __restrict__ xq, const float* __restrict__ xk,
    const float* __restrict__ x_invn,
    const float* __restrict__ adt, const float* __restrict__ posl,
    float* __restrict__ dsum) {
  int st = blockIdx.x, b = blockIdx.y, dir = blockIdx.z;
  const float* xsrc = dir == 0 ? xq : xk;
  const float* inv_src = x_invn + (dir ? 65536 : 0);
  const float* Bt = adt + dir * 8192;  // [128][64]

  __shared__ float red[16];

  int tid = threadIdx.x;
  int tx = tid & 15, ty = tid >> 4;
  int s0 = st * 64;
  const float* xb = xsrc + (size_t)b * 131072;

  // per-thread rows s = s0 + ty*4 + i; sinv for those 4 rows
  float4 sinv4 = *reinterpret_cast<const float4*>(inv_src + b * 1024 + s0 + ty * 4);

  float acc[4][4];
#pragma unroll
  for (int i = 0; i < 4; ++i)
#pragma unroll
    for (int j = 0; j < 4; ++j) acc[i][j] = 0.f;

  const float* arow = xb + s0 + ty * 4;  // + kk*1024
  const float* brow = Bt + tx * 4;       // + kk*64

#pragma unroll 4
  for (int kk = 0; kk < 128; ++kk) {
    float4 av = *reinterpret_cast<const float4*>(arow + (size_t)kk * 1024);
    float4 bv = *reinterpret_cast<const float4*>(brow + (size_t)kk * 64);
    // same single-rounding x*sinv as the old As2 staging
    float a[4] = {av.x * sinv4.x, av.y * sinv4.y, av.z * sinv4.z, av.w * sinv4.w};
    float bb[4] = {bv.x, bv.y, bv.z, bv.w};
#pragma unroll
    for (int i = 0; i < 4; ++i)
#pragma unroll
      for (int j = 0; j < 4; ++j) acc[i][j] += a[i] * bb[j];
  }

  float lsum = 0.f;
#pragma unroll
  for (int i = 0; i < 4; ++i) {
    int s = s0 + ty * 4 + i;
    float pos = posl[dir * 65536 + b * 1024 + s];  // already *10
    float lg[4];
    float mloc = -INFINITY;
#pragma unroll
    for (int j = 0; j < 4; ++j) {
      int jg = tx * 4 + j;
      lg[j] = (jg == b) ? -INFINITY : acc[i][j] * TEMP_INV;
      mloc = fmaxf(mloc, lg[j]);
    }
#pragma unroll
    for (int mask = 1; mask <= 8; mask <<= 1) mloc = fmaxf(mloc, __shfl_xor(mloc, mask));
    float m = fmaxf(mloc, pos);
    float e = 0.f;
#pragma unroll
    for (int j = 0; j < 4; ++j) e += __expf(lg[j] - m);
#pragma unroll
    for (int mask = 1; mask <= 8; mask <<= 1) e += __shfl_xor(e, mask);
    if (tx == 0) lsum += m + __logf(e + __expf(pos - m)) - pos;
  }
  if (tx == 0) red[ty] = lsum;
  __syncthreads();
  if (tid == 0) {
    float v = 0.f;
#pragma unroll
    for (int r = 0; r < 16; ++r) v += red[r];
    atomicAdd(dsum, v);
  }
}

__global__ void kfinal(const float* __restrict__ gsum, const float* __restrict__ dsum,
                       const int* __restrict__ epoch, float* __restrict__ out) {
  if (threadIdx.x == 0) {
    float g = gsum[0] / 128.0f;
    float dn = dsum[0] / 131072.0f;
    out[0] = (epoch[0] > 0) ? (0.5f * g + 0.5f * dn) : g;  // WARMUP=0, COEFF=0.5
  }
}

// ---------- launch ----------
extern "C" void kernel_launch(void* const* d_in, const int* in_sizes, int n_in,
                              void* d_out, int out_size, void* d_ws, size_t ws_size,
                              hipStream_t stream) {
  const float* ofq = (const float*)d_in[0];
  const float* agq = (const float*)d_in[1];
  const float* xq  = (const float*)d_in[2];
  const float* adq = (const float*)d_in[3];
  const float* ofk = (const float*)d_in[4];
  const float* agk = (const float*)d_in[5];
  const float* xk  = (const float*)d_in[6];
  const float* adk = (const float*)d_in[7];
  const int* epoch = (const int*)d_in[8];
  float* out = (float*)d_out;

  char* wsb = (char*)d_ws;
  __bf16* ofT = (__bf16*)wsb;                       // 64MB
  u64* best_row = (u64*)(wsb + 67108864);           // 512KB
  u64* best_col = best_row + 65536;                 // 512KB
  float* gsum = (float*)(best_col + 65536);
  float* dsum = gsum + 1;
  float* posl = dsum + 1;                           // 512KB
  float* x_invn  = posl + 131072;                   // 512KB
  float* of_invn = x_invn + 131072;                 // 512KB
  float* adt = of_invn + 131072;                    // 64KB

  // zero best arrays (packed 0 < any real key) + gsum + dsum in one memset
  hipMemsetAsync(best_row, 0, 65536ull * 8 * 2 + 8, stream);

  kpre<<<4736, 256, 0, stream>>>(ofq, ofk, ofT, of_invn, xq, xk, x_invn,
                                 adq, adk, adt, agq, agk, gsum);

  dim3 gs(4, 4, 64);
  ksim<<<gs, 512, 0, stream>>>(ofT, of_invn, best_row, best_col);

  dim3 gp(64, 2, 2);
  kpos<<<gp, 512, 0, stream>>>(xq, xk, x_invn, best_row, best_col, posl);

  dim3 gn(16, 64, 2);
  kneg<<<gn, 256, 0, stream>>>(xq, xk, x_invn, adt, posl, dsum);

  kfinal<<<1, 1, 0, stream>>>(gsum, dsum, epoch, out);
}

// Round 7
// 385.495 us; speedup vs baseline: 1.0808x; 1.0808x over previous
//
#include <hip/hip_runtime.h>
#include <math.h>

// Problem constants: B=64/side (128 concat), d=256, C=128, S=1024, TEMP=0.1, COEFF=0.5
#define TEMP_INV 10.0f

typedef unsigned long long u64;
typedef __attribute__((ext_vector_type(8))) __bf16 bf16x8;
typedef __attribute__((ext_vector_type(4))) float f32x4;

// Monotone u32 key: fkey(a) > fkey(b) iff a > b (floats, no NaN).
__device__ inline unsigned fkey(float v) {
  unsigned u = __float_as_uint(v);
  return (u & 0x80000000u) ? ~u : (u | 0x80000000u);
}

// async global->LDS, 16B per lane (wave-uniform base + lane*16 ordering).
__device__ __forceinline__ void async_copy16(const void* gp, void* lp) {
  __builtin_amdgcn_global_load_lds(
      (__attribute__((address_space(1))) void*)(unsigned long long)gp,
      (__attribute__((address_space(3))) void*)(unsigned long long)lp,
      16, 0, 0);
}

// ---------- merged prologue: kcvt [0,4096) + kprep [4096,4672) + kglobal [4672,4736) ----------
// R7 kcvt: single-latency restructure — all 32 independent loads issued up
// front (32 outstanding vs 4), per-iteration LDS regions T[8][...], ONE
// barrier (was 16). Same element assignment + same add order => bit-identical
// ofT / of_invn.
__global__ __launch_bounds__(256) void kpre(
    const float* __restrict__ ofq, const float* __restrict__ ofk,
    __bf16* __restrict__ ofT, float* __restrict__ of_invn,
    const float* __restrict__ xq, const float* __restrict__ xk,
    float* __restrict__ x_invn,
    const float* __restrict__ adq, const float* __restrict__ adk,
    float* __restrict__ adt,
    const float* __restrict__ agq, const float* __restrict__ agk,
    float* __restrict__ gsum) {
  unsigned bx = blockIdx.x;
  int t = threadIdx.x;
  if (bx < 4096) {
    // ---- kcvt: fused transpose + bf16 convert + norms ----
    int s0 = (bx & 31) * 32, b = bx >> 5;
    const float* src = (b < 64) ? (ofq + (size_t)b * 262144) : (ofk + (size_t)(b - 64) * 262144);
    __shared__ __bf16 T[8][32][36];  // 18432 B: per-iteration tiles, no reuse hazard
    __shared__ float R[8][32];
    int dd = t >> 5, ss = t & 31;
    int wr = t >> 3, wd = t & 7;
    float v[8][4];
    // phase 0: all 32 independent loads in flight
#pragma unroll
    for (int d0i = 0; d0i < 8; ++d0i)
#pragma unroll
      for (int it = 0; it < 4; ++it)
        v[d0i][it] = src[(size_t)(d0i * 32 + dd + 8 * it) * 1024 + s0 + ss];
    // ssq in the exact original order (d0 asc, it asc)
    float ssq = 0.f;
#pragma unroll
    for (int d0i = 0; d0i < 8; ++d0i)
#pragma unroll
      for (int it = 0; it < 4; ++it) ssq += v[d0i][it] * v[d0i][it];
    // phase 1: all transpose tiles + norm partials into LDS
#pragma unroll
    for (int d0i = 0; d0i < 8; ++d0i)
#pragma unroll
      for (int it = 0; it < 4; ++it) T[d0i][ss][dd + 8 * it] = (__bf16)v[d0i][it];
    R[dd][ss] = ssq;
    __syncthreads();  // the only barrier
    // phase 2: all output writes
    __bf16* out = ofT + (size_t)b * 262144 + (size_t)s0 * 256;
#pragma unroll
    for (int d0i = 0; d0i < 8; ++d0i)
      *(uint2*)(out + (size_t)wr * 256 + d0i * 32 + wd * 4) = *(const uint2*)(&T[d0i][wr][wd * 4]);
    if (t < 32) {
      float a = 0.f;
#pragma unroll
      for (int r = 0; r < 8; ++r) a += R[r][t];
      of_invn[b * 1024 + s0 + t] = 1.0f / fmaxf(sqrtf(a), 1e-12f);
    }
  } else if (bx < 4672) {
    // ---- kprep: x-norms + ad transpose ----
    unsigned px = bx - 4096;
    if (px < 512) {
      int idx = px * 256 + t;  // 0..131071
      int b = idx >> 10, s = idx & 1023;
      const float* src = (b < 64) ? (xq + (size_t)b * 131072) : (xk + (size_t)(b - 64) * 131072);
      float acc = 0.f;
#pragma unroll 8
      for (int c = 0; c < 128; ++c) { float v = src[c * 1024 + s]; acc += v * v; }
      x_invn[idx] = 1.0f / fmaxf(sqrtf(acc), 1e-12f);
    } else {
      int i = (px - 512) * 256 + t;  // 0..16383
      int dir = i >> 13, r = i & 8191;
      int j = r >> 7, c = r & 127;
      const float* ad = dir == 0 ? adk : adq;
      adt[dir * 8192 + c * 64 + j] = ad[j * 128 + c];
    }
  } else {
    // ---- kglobal: 2 rows i per block (t<128 -> i0, t>=128 -> i0+1) ----
    __shared__ float logits[2][128];
    __shared__ float rinv[128];
    int ii = t >> 7, j = t & 127;
    int i = (int)(bx - 4672) * 2 + ii;
    const float* rowi = (i < 64) ? (agq + i * 128) : (agk + (i - 64) * 128);
    const float* rowj = (j < 64) ? (agq + j * 128) : (agk + (j - 64) * 128);
    float dot = 0.f, nj = 0.f;
#pragma unroll 8
    for (int c = 0; c < 128; ++c) { float a = rowi[c], bb = rowj[c]; dot += a * bb; nj += bb * bb; }
    if (ii == 0) rinv[j] = 1.0f / fmaxf(sqrtf(nj), 1e-12f);
    __syncthreads();
    logits[ii][j] = dot * rinv[i] * rinv[j] * TEMP_INV;
    __syncthreads();
    if (j == 0) {
      int pos = (i + 64) & 127;
      float m = -INFINITY;
      for (int tt = 0; tt < 128; ++tt) if (tt != i) m = fmaxf(m, logits[ii][tt]);
      float e = 0.f;
      for (int tt = 0; tt < 128; ++tt) if (tt != i) e += __expf(logits[ii][tt] - m);
      atomicAdd(gsum, m + __logf(e) - logits[ii][pos]);
    }
  }
}

// ---------- MFMA sim GEMM + dual argmax (R5 best: 92 us, FETCH 33 MB) ----------
// 256x256 tile, 8 waves (2M x 4N), BK=64, double-buffered, G4 XOR-swizzled LDS,
// b<->XCD affinity swizzle (b-slice L2-resident on one XCD).
__global__ __launch_bounds__(512, 2) void ksim(
    const __bf16* __restrict__ ofT, const float* __restrict__ of_invn,
    u64* __restrict__ best_row, u64* __restrict__ best_col) {
  // hardware linear block id -> (xcd, slot); b % 8 == xcd; 1024 = 8 XCD x 128
  unsigned h = blockIdx.x + (blockIdx.y << 2) + (blockIdx.z << 4);
  int xcd = h & 7;
  unsigned slot = h >> 3;               // 0..127 within XCD
  int b = xcd + 8 * (int)(slot >> 4);   // 16 tiles per b
  int tile = slot & 15;
  int s0 = (tile & 3) * 256, t0 = (tile >> 2) * 256;

  const __bf16* Ag = ofT + (size_t)b * 262144;        // q rows [1024][256]
  const __bf16* Bg = ofT + (size_t)(b + 64) * 262144; // k rows
  __shared__ __bf16 As[2][16384];  // 64 KiB
  __shared__ __bf16 Bs[2][16384];  // 64 KiB  (total 128 KiB)

  int t = threadIdx.x;
  int lane = t & 63, w = t >> 6;
  int lc = lane & 15, q = lane >> 4;
  int wm = w >> 2, wn = w & 3;  // 2 x 4 wave grid; wave owns 128(M) x 64(N)

  f32x4 acc[8][4];
#pragma unroll
  for (int i = 0; i < 8; ++i)
#pragma unroll
    for (int j = 0; j < 4; ++j) acc[i][j] = (f32x4)(0.f);

  // fragment LDS offsets (bf16 units), kk=0; kk=1 reads offset ^ 32
  int aoff[8], boff[4];
#pragma unroll
  for (int i = 0; i < 8; ++i) {
    int mr = wm * 128 + i * 16 + lc;
    aoff[i] = mr * 64 + ((q ^ (mr & 7)) << 3);
  }
#pragma unroll
  for (int j = 0; j < 4; ++j) {
    int nc = wn * 64 + j * 16 + lc;
    boff[j] = nc * 64 + ((q ^ (nc & 7)) << 3);
  }

  // staging: thread t, chunk c: row m = c*64 + (t>>3), phys slot g = t&7,
  // logical group lg = g ^ (m&7) = g ^ ((t>>3)&7)  (c*64 is 0 mod 8)
  int ms = t >> 3, gphys = t & 7;
  int lg = gphys ^ (ms & 7);
  size_t aSrc = (size_t)(s0 + ms) * 256 + lg * 8;
  size_t bSrc = (size_t)(t0 + ms) * 256 + lg * 8;

  auto STAGE = [&](int bufn, int k0) {
    char* aL = (char*)&As[bufn][0] + t * 16;
    char* bL = (char*)&Bs[bufn][0] + t * 16;
#pragma unroll
    for (int c = 0; c < 4; ++c) {
      async_copy16(Ag + aSrc + (size_t)c * 16384 + k0, aL + c * 8192);
      async_copy16(Bg + bSrc + (size_t)c * 16384 + k0, bL + c * 8192);
    }
  };

  // prologue: stage k0=0 into buf 0
  STAGE(0, 0);
  __syncthreads();

  for (int it = 0; it < 4; ++it) {
    int buf = it & 1;
    if (it < 3) STAGE(buf ^ 1, (it + 1) * 64);
#pragma unroll
    for (int kk = 0; kk < 2; ++kk) {
      int kx = kk << 5;  // ^32 toggles phys k-group bit 2
      bf16x8 af[8], bfr[4];
#pragma unroll
      for (int i = 0; i < 8; ++i) af[i] = *(const bf16x8*)(&As[buf][0] + (aoff[i] ^ kx));
#pragma unroll
      for (int j = 0; j < 4; ++j) bfr[j] = *(const bf16x8*)(&Bs[buf][0] + (boff[j] ^ kx));
      __builtin_amdgcn_s_setprio(1);
#pragma unroll
      for (int i = 0; i < 8; ++i)
#pragma unroll
        for (int j = 0; j < 4; ++j)
          acc[i][j] = __builtin_amdgcn_mfma_f32_16x16x32_bf16(af[i], bfr[j], acc[i][j], 0, 0, 0);
      __builtin_amdgcn_s_setprio(0);
    }
    __syncthreads();  // readers done with buf + drains prefetch vmcnt
  }

  // ---- epilogue (f32 domain). C/D layout: col=lane&15, row=(lane>>4)*4+reg ----
  float sk[4];
#pragma unroll
  for (int j = 0; j < 4; ++j) sk[j] = of_invn[65536 + b * 1024 + t0 + wn * 64 + j * 16 + lc];
  float sq[32];
#pragma unroll
  for (int i = 0; i < 8; ++i)
#pragma unroll
    for (int e = 0; e < 4; ++e)
      sq[i * 4 + e] = of_invn[b * 1024 + s0 + wm * 128 + i * 16 + q * 4 + e];

  u64* browb = best_row + (size_t)b * 1024 + s0;
  u64* bcolb = best_col + (size_t)b * 1024 + t0;

  // row direction: argmax over t for fixed s (scale by sik only; siq>0 dropped)
#pragma unroll
  for (int i = 0; i < 8; ++i) {
#pragma unroll
    for (int e = 0; e < 4; ++e) {
      float v[4];
#pragma unroll
      for (int j = 0; j < 4; ++j) v[j] = acc[i][j][e] * sk[j];
      float vb = fmaxf(fmaxf(v[0], v[1]), fmaxf(v[2], v[3]));
#pragma unroll
      for (int mask = 1; mask <= 8; mask <<= 1) vb = fmaxf(vb, __shfl_xor(vb, mask));
      unsigned ib = 0xFFFFFFFFu;
#pragma unroll
      for (int j = 0; j < 4; ++j) {
        unsigned cand = (v[j] == vb) ? (unsigned)(t0 + wn * 64 + j * 16 + lc) : 0xFFFFFFFFu;
        ib = min(ib, cand);
      }
#pragma unroll
      for (int mask = 1; mask <= 8; mask <<= 1) ib = min(ib, __shfl_xor(ib, mask));
      if (lc == 0)
        atomicMax(browb + wm * 128 + i * 16 + q * 4 + e,
                  ((u64)fkey(vb) << 32) | (u64)(0xFFFFFFFFu - ib));
    }
  }

  // col direction: argmax over s for fixed t (scale by siq only)
#pragma unroll
  for (int j = 0; j < 4; ++j) {
    float cb = -INFINITY;
#pragma unroll
    for (int i = 0; i < 8; ++i)
#pragma unroll
      for (int e = 0; e < 4; ++e) cb = fmaxf(cb, acc[i][j][e] * sq[i * 4 + e]);
    cb = fmaxf(cb, __shfl_xor(cb, 16));
    cb = fmaxf(cb, __shfl_xor(cb, 32));
    unsigned ib = 0xFFFFFFFFu;
#pragma unroll
    for (int i = 0; i < 8; ++i)
#pragma unroll
      for (int e = 0; e < 4; ++e) {
        float m2 = acc[i][j][e] * sq[i * 4 + e];  // bitwise-identical recompute
        unsigned cand = (m2 == cb) ? (unsigned)(s0 + wm * 128 + i * 16 + q * 4 + e) : 0xFFFFFFFFu;
        ib = min(ib, cand);
      }
    ib = min(ib, __shfl_xor(ib, 16));
    ib = min(ib, __shfl_xor(ib, 32));
    if (lane < 16)
      atomicMax(bcolb + wn * 64 + j * 16 + lane,
                ((u64)fkey(cb) << 32) | (u64)(0xFFFFFFFFu - ib));
  }
}

// ---------- pos logits (R5-proven version) ----------
// One 1024-thread block per (b,dir); x_dst staged into LDS exactly once.
__global__ __launch_bounds__(1024) void kpos(
    const float* __restrict__ xq, const float* __restrict__ xk,
    const float* __restrict__ x_invn,
    const u64* __restrict__ best_row, const u64* __restrict__ best_col,
    float* __restrict__ posl) {
  int b = blockIdx.x, dir = blockIdx.y;
  const float* xsrc = dir == 0 ? xq : xk;
  const float* xdst = dir == 0 ? xk : xq;
  const float* inv_src = x_invn + (dir ? 65536 : 0);
  const float* inv_dst = x_invn + (dir ? 0 : 65536);
  const u64* best = dir == 0 ? best_row : best_col;

  __shared__ float xrow[8][1024];  // 32KB
  __shared__ float sdinv[1024];
  int t = threadIdx.x;  // = s
  sdinv[t] = inv_dst[b * 1024 + t];
  u64 p = best[(size_t)b * 1024 + t];
  int sidx = (int)(0xFFFFFFFFu - (unsigned)(p & 0xFFFFFFFFull));
  const float* xsb = xsrc + (size_t)b * 131072;
  const float* xdb = xdst + (size_t)b * 131072;
  float acc = 0.f;
  for (int c0 = 0; c0 < 128; c0 += 8) {
    __syncthreads();
#pragma unroll
    for (int qq = 0; qq < 2; ++qq)
      ((float4*)xrow)[t + 1024 * qq] = ((const float4*)(xdb + (size_t)c0 * 1024))[t + 1024 * qq];
    __syncthreads();
#pragma unroll
    for (int cc = 0; cc < 8; ++cc)
      acc += xsb[(size_t)(c0 + cc) * 1024 + t] * xrow[cc][sidx];
  }
  posl[dir * 65536 + b * 1024 + t] = acc * inv_src[b * 1024 + t] * sdinv[sidx] * TEMP_INV;
}

// ---------- neg GEMM + fused logsumexp (R5-proven staged version) ----------
__global__ __launch_bounds__(256) void kneg(
    const float* __restrict__ xq, const float* __restrict__ xk,
    const float* __restrict__ x_invn,
    const float* __restrict__ adt, const float* __restrict__ posl,
    float* __restrict__ dsum) {
  int st = blockIdx.x, b = blockIdx.y, dir = blockIdx.z;
  const float* xsrc = dir == 0 ? xq : xk;
  const float* inv_src = x_invn + (dir ? 65536 : 0);
  const float* Bt = adt + dir * 8192;  // [128][64]

  __shared__ float As2[64][64];
  __shared__ float Bs2[128][64];
  __shared__ float red[16];

  int tid = threadIdx.x;
  int tx = tid & 15, ty = tid >> 4;
  int s0 = st * 64;

#pragma unroll
  for (int qq = 0; qq < 8; ++qq)
    reinterpret_cast<float4*>(Bs2)[tid + 256 * qq] =
        reinterpret_cast<const float4*>(Bt)[tid + 256 * qq];

  float acc[4][4];
#pragma unroll
  for (int i = 0; i < 4; ++i)
#pragma unroll
    for (int j = 0; j < 4; ++j) acc[i][j] = 0.f;

  int lm = tid & 63, lk = tid >> 6;
  float sinv = inv_src[b * 1024 + s0 + lm];
  const float* xb = xsrc + (size_t)b * 131072;

  for (int k0 = 0; k0 < 128; k0 += 64) {
#pragma unroll
    for (int r = 0; r < 16; ++r) {
      int kk = lk + 4 * r;
      As2[kk][lm] = xb[(k0 + kk) * 1024 + s0 + lm] * sinv;
    }
    __syncthreads();
#pragma unroll
    for (int kk = 0; kk < 64; ++kk) {
      float4 av = *reinterpret_cast<const float4*>(&As2[kk][ty * 4]);
      float4 bv = *reinterpret_cast<const float4*>(&Bs2[k0 + kk][tx * 4]);
      float a[4] = {av.x, av.y, av.z, av.w};
      float bb[4] = {bv.x, bv.y, bv.z, bv.w};
#pragma unroll
      for (int i = 0; i < 4; ++i)
#pragma unroll
        for (int j = 0; j < 4; ++j) acc[i][j] += a[i] * bb[j];
    }
    __syncthreads();
  }

  float lsum = 0.f;
#pragma unroll
  for (int i = 0; i < 4; ++i) {
    int s = s0 + ty * 4 + i;
    float pos = posl[dir * 65536 + b * 1024 + s];  // already *10
    float lg[4];
    float mloc = -INFINITY;
#pragma unroll
    for (int j = 0; j < 4; ++j) {
      int jg = tx * 4 + j;
      lg[j] = (jg == b) ? -INFINITY : acc[i][j] * TEMP_INV;
      mloc = fmaxf(mloc, lg[j]);
    }
#pragma unroll
    for (int mask = 1; mask <= 8; mask <<= 1) mloc = fmaxf(mloc, __shfl_xor(mloc, mask));
    float m = fmaxf(mloc, pos);
    float e = 0.f;
#pragma unroll
    for (int j = 0; j < 4; ++j) e += __expf(lg[j] - m);
#pragma unroll
    for (int mask = 1; mask <= 8; mask <<= 1) e += __shfl_xor(e, mask);
    if (tx == 0) lsum += m + __logf(e + __expf(pos - m)) - pos;
  }
  if (tx == 0) red[ty] = lsum;
  __syncthreads();
  if (tid == 0) {
    float v = 0.f;
#pragma unroll
    for (int r = 0; r < 16; ++r) v += red[r];
    atomicAdd(dsum, v);
  }
}

__global__ void kfinal(const float* __restrict__ gsum, const float* __restrict__ dsum,
                       const int* __restrict__ epoch, float* __restrict__ out) {
  if (threadIdx.x == 0) {
    float g = gsum[0] / 128.0f;
    float dn = dsum[0] / 131072.0f;
    out[0] = (epoch[0] > 0) ? (0.5f * g + 0.5f * dn) : g;  // WARMUP=0, COEFF=0.5
  }
}

// ---------- launch ----------
extern "C" void kernel_launch(void* const* d_in, const int* in_sizes, int n_in,
                              void* d_out, int out_size, void* d_ws, size_t ws_size,
                              hipStream_t stream) {
  const float* ofq = (const float*)d_in[0];
  const float* agq = (const float*)d_in[1];
  const float* xq  = (const float*)d_in[2];
  const float* adq = (const float*)d_in[3];
  const float* ofk = (const float*)d_in[4];
  const float* agk = (const float*)d_in[5];
  const float* xk  = (const float*)d_in[6];
  const float* adk = (const float*)d_in[7];
  const int* epoch = (const int*)d_in[8];
  float* out = (float*)d_out;

  char* wsb = (char*)d_ws;
  __bf16* ofT = (__bf16*)wsb;                       // 64MB
  u64* best_row = (u64*)(wsb + 67108864);           // 512KB
  u64* best_col = best_row + 65536;                 // 512KB
  float* gsum = (float*)(best_col + 65536);
  float* dsum = gsum + 1;
  float* posl = dsum + 1;                           // 512KB
  float* x_invn  = posl + 131072;                   // 512KB
  float* of_invn = x_invn + 131072;                 // 512KB
  float* adt = of_invn + 131072;                    // 64KB

  // zero best arrays (packed 0 < any real key) + gsum + dsum in one memset
  hipMemsetAsync(best_row, 0, 65536ull * 8 * 2 + 8, stream);

  kpre<<<4736, 256, 0, stream>>>(ofq, ofk, ofT, of_invn, xq, xk, x_invn,
                                 adq, adk, adt, agq, agk, gsum);

  dim3 gs(4, 4, 64);
  ksim<<<gs, 512, 0, stream>>>(ofT, of_invn, best_row, best_col);

  dim3 gp(64, 2);
  kpos<<<gp, 1024, 0, stream>>>(xq, xk, x_invn, best_row, best_col, posl);

  dim3 gn(16, 64, 2);
  kneg<<<gn, 256, 0, stream>>>(xq, xk, x_invn, adt, posl, dsum);

  kfinal<<<1, 1, 0, stream>>>(gsum, dsum, epoch, out);
}